// Round 6
// baseline (337.914 us; speedup 1.0000x reference)
//
#include <hip/hip_runtime.h>
#include <hip/hip_bf16.h>

// B=8, L=1024, D=1024, H=16, HD=64
#define B_ 8
#define L_ 1024
#define D_ 1024
#define H_ 16
#define HD_ 64

typedef short short8 __attribute__((ext_vector_type(8)));
typedef float floatx4 __attribute__((ext_vector_type(4)));
typedef unsigned short u16;

__device__ __forceinline__ u16 f2bf(float f) {          // RNE
  union { float f; unsigned u; } v; v.f = f;
  unsigned r = v.u + 0x7fffu + ((v.u >> 16) & 1u);
  return (u16)(r >> 16);
}
// pack bf16(a) low16, bf16(b) high16
__device__ __forceinline__ unsigned pk2(float a, float b) {
  union { float f; unsigned u; } x, y; x.f = a; y.f = b;
  return __builtin_amdgcn_perm(y.u + 0x8000u, x.u + 0x8000u, 0x07060302u);
}
__device__ __forceinline__ floatx4 mfma16(short8 a, short8 b, floatx4 c) {
  return __builtin_amdgcn_mfma_f32_16x16x32_bf16(a, b, c, 0, 0, 0);
}
__device__ __forceinline__ void gl2lds16(const void* g, void* l) {
  __builtin_amdgcn_global_load_lds(
      (const __attribute__((address_space(1))) void*)g,
      (__attribute__((address_space(3))) void*)l, 16, 0, 0);
}

#define KSCALE 0.04508422f   // log2(e)/32 folded into K projection

// ---- 3x: x fp32 [8M] -> bf16, grid (4096, nsel) ----
__global__ __launch_bounds__(256) void cvtx3_k(const float* __restrict__ x0,
    const float* __restrict__ x1, const float* __restrict__ x2,
    u16* __restrict__ y0, u16* __restrict__ y1, u16* __restrict__ y2) {
  const float* x = blockIdx.y == 0 ? x0 : (blockIdx.y == 1 ? x1 : x2);
  u16* y = blockIdx.y == 0 ? y0 : (blockIdx.y == 1 ? y1 : y2);
  size_t i = ((size_t)blockIdx.x * 256 + threadIdx.x) * 8;
  float4 a = *(const float4*)(x + i);
  float4 b = *(const float4*)(x + i + 4);
  uint4 u = make_uint4(pk2(a.x, a.y), pk2(a.z, a.w), pk2(b.x, b.y), pk2(b.z, b.w));
  *(uint4*)(y + i) = u;
}

// ---- 4x: W [K,N] fp32 -> Wt [N][K] bf16, grid (16,16,4) ----
__global__ __launch_bounds__(256) void cvtw4_k(
    const float* __restrict__ W0, const float* __restrict__ W1,
    const float* __restrict__ W2, const float* __restrict__ W3,
    u16* __restrict__ T0, u16* __restrict__ T1,
    u16* __restrict__ T2, u16* __restrict__ T3) {
  const int z = blockIdx.z;
  const float* W = z == 0 ? W0 : (z == 1 ? W1 : (z == 2 ? W2 : W3));
  u16* Wt = z == 0 ? T0 : (z == 1 ? T1 : (z == 2 ? T2 : T3));
  const int kt = blockIdx.x, nt = blockIdx.y;
  __shared__ __align__(16) u16 t[64 * 72];
  const int tid = threadIdx.x;
  #pragma unroll
  for (int i = 0; i < 4; ++i) {
    int idx = i * 256 + tid;
    int r = idx >> 4, c4 = idx & 15;
    float4 v = *(const float4*)(W + (size_t)(kt * 64 + r) * 1024 + nt * 64 + c4 * 4);
    t[(c4 * 4 + 0) * 72 + r] = f2bf(v.x);
    t[(c4 * 4 + 1) * 72 + r] = f2bf(v.y);
    t[(c4 * 4 + 2) * 72 + r] = f2bf(v.z);
    t[(c4 * 4 + 3) * 72 + r] = f2bf(v.w);
  }
  __syncthreads();
  #pragma unroll
  for (int i = 0; i < 2; ++i) {
    int idx = i * 256 + tid;
    int n = idx >> 3, k8 = idx & 7;
    short8 v = *(const short8*)(&t[n * 72 + k8 * 8]);
    *(short8*)(Wt + (size_t)(nt * 64 + n) * 1024 + kt * 64 + k8 * 8) = v;
  }
}

// ---- GEMM: C[8192,1024] = A @ Wt^T + bias ----  BK=64
// grid (64, 8): x=mt, y=nt -> A-slab sharers land on the same XCD (id%8)
// AMODE: 0 = A fp32, 1 = A bf16
// OUTM : 0 = fp32 [M,N]; 1 = bf16 head [B,H,L,HD], scaled by `scale`;
//        2 = bf16 V^T [B*D][L] scaled by inv[key], keys PERMUTED within
//            32-groups: pos = g*32 + quad*8 + kt*4 + r  <- key g*32+kt*16+quad*4+r
template<int AMODE, int OUTM>
__global__ __launch_bounds__(256, 2) void gemm2_k(const void* __restrict__ Ap,
    const u16* __restrict__ Bt, const float* __restrict__ bias,
    void* __restrict__ Cp, const float* __restrict__ inv, float scale)
{
  const int mt = blockIdx.x, nt = blockIdx.y;
  const int tid = threadIdx.x, lane = tid & 63, w = tid >> 6;
  const int quad = lane >> 4, l16 = lane & 15;
  const int wm = w >> 1, wn = w & 1;
  const int m0 = mt * 128, n0 = nt * 128;

  constexpr int ABYTES = AMODE ? 16384 : 32768;
  constexpr int STG = ABYTES + 16384;
  constexpr int SBYTES = (OUTM == 2 && STG < 34816) ? 34816 : STG;
  __shared__ __align__(16) char smem[SBYTES];
  char* AsB = smem;
  char* BsB = smem + ABYTES;

  const floatx4 fz = {0.f, 0.f, 0.f, 0.f};
  floatx4 acc[4][4];
  #pragma unroll
  for (int i = 0; i < 4; ++i)
    #pragma unroll
    for (int j = 0; j < 4; ++j) acc[i][j] = fz;

  for (int k0 = 0; k0 < 1024; k0 += 64) {
    #pragma unroll
    for (int seg = 0; seg < 4; ++seg) {
      int cI = seg * 256 + w * 64 + lane;
      int r = cI >> 3, sl = cI & 7;
      int kc = sl ^ (r & 7);
      gl2lds16(Bt + (size_t)(n0 + r) * 1024 + k0 + kc * 8, BsB + cI * 16);
    }
    if constexpr (AMODE == 0) {   // A fp32: 128 rows x 256B, 16 slots
      const float* A = (const float*)Ap;
      #pragma unroll
      for (int seg = 0; seg < 8; ++seg) {
        int cI = seg * 256 + w * 64 + lane;
        int r = cI >> 4, sl = cI & 15;
        int kc = sl ^ (r & 15);
        gl2lds16(A + (size_t)(m0 + r) * 1024 + k0 + kc * 4, AsB + cI * 16);
      }
    } else {                      // A bf16: 128 rows x 128B, 8 slots
      const u16* A = (const u16*)Ap;
      #pragma unroll
      for (int seg = 0; seg < 4; ++seg) {
        int cI = seg * 256 + w * 64 + lane;
        int r = cI >> 3, sl = cI & 7;
        int kc = sl ^ (r & 7);
        gl2lds16(A + (size_t)(m0 + r) * 1024 + k0 + kc * 8, AsB + cI * 16);
      }
    }
    __syncthreads();

    #pragma unroll
    for (int ks = 0; ks < 2; ++ks) {
      short8 af[4], bfv[4];
      #pragma unroll
      for (int mf = 0; mf < 4; ++mf) {
        int row = wm * 64 + mf * 16 + l16;
        if constexpr (AMODE == 0) {
          int L0 = ks * 8 + quad * 2;
          float4 x0 = *(const float4*)(AsB + row * 256 + ((L0) ^ l16) * 16);
          float4 x1 = *(const float4*)(AsB + row * 256 + ((L0 + 1) ^ l16) * 16);
          union { uint4 u; short8 s; } uu;
          uu.u = make_uint4(pk2(x0.x, x0.y), pk2(x0.z, x0.w),
                            pk2(x1.x, x1.y), pk2(x1.z, x1.w));
          af[mf] = uu.s;
        } else {
          af[mf] = *(const short8*)(AsB + row * 128 + (((ks * 4 + quad) ^ (l16 & 7)) * 16));
        }
      }
      #pragma unroll
      for (int nf = 0; nf < 4; ++nf) {
        int row = wn * 64 + nf * 16 + l16;
        bfv[nf] = *(const short8*)(BsB + row * 128 + (((ks * 4 + quad) ^ (l16 & 7)) * 16));
      }
      #pragma unroll
      for (int mf = 0; mf < 4; ++mf)
        #pragma unroll
        for (int nf = 0; nf < 4; ++nf)
          acc[mf][nf] = mfma16(af[mf], bfv[nf], acc[mf][nf]);
    }
    __syncthreads();
  }

  float bv[4];
  #pragma unroll
  for (int nf = 0; nf < 4; ++nf) bv[nf] = bias[n0 + wn * 64 + nf * 16 + l16];

  if constexpr (OUTM == 0) {
    float* C = (float*)Cp;
    #pragma unroll
    for (int mf = 0; mf < 4; ++mf)
      #pragma unroll
      for (int nf = 0; nf < 4; ++nf) {
        int n = n0 + wn * 64 + nf * 16 + l16;
        #pragma unroll
        for (int r = 0; r < 4; ++r) {
          int m = m0 + wm * 64 + mf * 16 + quad * 4 + r;
          C[(size_t)m * 1024 + n] = acc[mf][nf][r] + bv[nf];
        }
      }
  } else if constexpr (OUTM == 1) {
    u16* C = (u16*)Cp;
    #pragma unroll
    for (int mf = 0; mf < 4; ++mf)
      #pragma unroll
      for (int nf = 0; nf < 4; ++nf) {
        int n = n0 + wn * 64 + nf * 16 + l16;
        #pragma unroll
        for (int r = 0; r < 4; ++r) {
          int m = m0 + wm * 64 + mf * 16 + quad * 4 + r;
          int bb = m >> 10, l = m & 1023, hh = n >> 6, hd = n & 63;
          C[((size_t)((bb * H_ + hh) * L_) + l) * HD_ + hd] =
              f2bf((acc[mf][nf][r] + bv[nf]) * scale);
        }
      }
  } else {  // OUTM == 2: scaled V^T, permuted key order
    u16* ct = (u16*)smem;            // 128 x 136 u16
    const int bb = m0 >> 10;
    const int hrow = bb * 16 + (n0 >> 6) + wn;
    float ivv[4][4];
    #pragma unroll
    for (int mf = 0; mf < 4; ++mf)
      #pragma unroll
      for (int r = 0; r < 4; ++r)
        ivv[mf][r] = inv[(size_t)hrow * 1024 + (m0 & 1023) + wm * 64 + mf * 16 + quad * 4 + r];
    __syncthreads();
    #pragma unroll
    for (int mf = 0; mf < 4; ++mf)
      #pragma unroll
      for (int nf = 0; nf < 4; ++nf)
        #pragma unroll
        for (int r = 0; r < 4; ++r) {
          float val = (acc[mf][nf][r] + bv[nf]) * ivv[mf][r];
          ct[(wn * 64 + nf * 16 + l16) * 136 + wm * 64 + mf * 16 + quad * 4 + r] = f2bf(val);
        }
    __syncthreads();
    u16* Vt = (u16*)Cp;
    #pragma unroll
    for (int i = 0; i < 8; ++i) {
      int cc = i * 256 + tid;
      int n = cc >> 4, l8 = cc & 15;
      int g = l8 >> 2, q2 = l8 & 3;
      int mloc = g * 32 + q2 * 4;
      uint2 lo = *(const uint2*)(&ct[n * 136 + mloc]);
      uint2 hi = *(const uint2*)(&ct[n * 136 + mloc + 16]);
      uint4 uv = make_uint4(lo.x, lo.y, hi.x, hi.y);
      *(uint4*)(Vt + ((size_t)bb * 1024 + n0 + n) * 1024 + (m0 & 1023) + l8 * 8) = uv;
    }
  }
}

// ---- colsum: inv[b,h,k] = 1/sum_q exp2(S'[q,k]); K pre-scaled by log2e/32 ----
// grid (128, 4): x = head (same-head blocks share an XCD), y = ktb
__global__ __launch_bounds__(256, 2) void colsum2_k(const u16* __restrict__ Q,
    const u16* __restrict__ K, float* __restrict__ inv)
{
  const int hh = blockIdx.x, ktb = blockIdx.y;
  const int tid = threadIdx.x, lane = tid & 63, w = tid >> 6;
  const int quad = lane >> 4, l16 = lane & 15;
  const size_t hb = (size_t)hh * L_ * HD_;
  const u16* Qh = Q + hb;
  const u16* Kh = K + hb;
  const int kbase = ktb * 256 + w * 64;
  const floatx4 fz = {0.f, 0.f, 0.f, 0.f};

  __shared__ __align__(16) u16 qsm[16384];   // 256 q-rows x 64 bf16, swizzled

  short8 kf[4][2];
  #pragma unroll
  for (int nf = 0; nf < 4; ++nf)
    #pragma unroll
    for (int ks = 0; ks < 2; ++ks)
      kf[nf][ks] = *(const short8*)(Kh + (size_t)(kbase + nf * 16 + l16) * 64 + ks * 32 + quad * 8);

  float cs[4] = {0.f, 0.f, 0.f, 0.f};
  for (int qc = 0; qc < 4; ++qc) {
    #pragma unroll
    for (int seg = 0; seg < 8; ++seg) {
      int cI = seg * 256 + w * 64 + lane;
      int row = cI >> 3, sl = cI & 7;
      gl2lds16(Qh + (size_t)(qc * 256 + row) * 64 + ((sl ^ (row & 7)) * 8), (char*)qsm + cI * 16);
    }
    __syncthreads();
    #pragma unroll
    for (int mf = 0; mf < 16; ++mf) {
      short8 qf0 = *(const short8*)(&qsm[(mf * 16 + l16) * 64 + ((quad ^ (l16 & 7)) * 8)]);
      short8 qf1 = *(const short8*)(&qsm[(mf * 16 + l16) * 64 + (((4 + quad) ^ (l16 & 7)) * 8)]);
      floatx4 sacc[4];
      #pragma unroll
      for (int nf = 0; nf < 4; ++nf) {
        floatx4 s = mfma16(qf0, kf[nf][0], fz);
        sacc[nf] = mfma16(qf1, kf[nf][1], s);
      }
      #pragma unroll
      for (int nf = 0; nf < 4; ++nf)
        #pragma unroll
        for (int r = 0; r < 4; ++r)
          cs[nf] += __builtin_amdgcn_exp2f(sacc[nf][r]);
    }
    __syncthreads();
  }
  #pragma unroll
  for (int nf = 0; nf < 4; ++nf) {
    cs[nf] += __shfl_xor(cs[nf], 16);
    cs[nf] += __shfl_xor(cs[nf], 32);
  }
  if (quad == 0) {
    #pragma unroll
    for (int nf = 0; nf < 4; ++nf)
      inv[(size_t)hh * L_ + kbase + nf * 16 + l16] = 1.0f / cs[nf];
  }
}

// ---- attention, NO K/V LDS staging (K/V are L2-resident per XCD) ----
// grid (128, 4): x = head, y = qb (256 q-rows/block, 64/wave).
// All operand fragments load straight from global (the unswizzled form of the
// verified LDS mapping); no __syncthreads in the main loop at all.
__global__ __launch_bounds__(256, 2) void attn4_k(const u16* __restrict__ Q,
    const u16* __restrict__ K, const u16* __restrict__ Vt, u16* __restrict__ O)
{
  const int hh = blockIdx.x, qb = blockIdx.y;
  const int b = hh >> 4, h = hh & 15;
  const int tid = threadIdx.x, lane = tid & 63, w = tid >> 6;
  const int quad = lane >> 4, l16 = lane & 15;
  const size_t hb = (size_t)hh * L_ * HD_;
  const u16* Qh = Q + hb;
  const u16* Kh = K + hb;
  const u16* Vh = Vt + ((size_t)b * D_ + h * HD_) * L_;   // [d][pos], stride L
  const int q0 = qb * 256 + w * 64;
  const floatx4 fz = {0.f, 0.f, 0.f, 0.f};

  __shared__ __align__(16) u16 smem[18432];   // epilogue transpose only

  short8 qf[4][2];            // B-operand frags of Q
  #pragma unroll
  for (int qs = 0; qs < 4; ++qs)
    #pragma unroll
    for (int ks = 0; ks < 2; ++ks)
      qf[qs][ks] = *(const short8*)(Qh + (size_t)(q0 + qs * 16 + l16) * 64 + ks * 32 + quad * 8);

  floatx4 oT[4][4];           // O^T: row d=ds*16+quad*4+r, col q=qs*16+l16
  #pragma unroll
  for (int i = 0; i < 4; ++i)
    #pragma unroll
    for (int j = 0; j < 4; ++j) oT[i][j] = fz;

  for (int kc = 0; kc < 16; ++kc) {
    const int kk = kc * 64;
    #pragma unroll
    for (int p = 0; p < 2; ++p) {             // 2 groups of 32 keys
      short8 ka0[2], ka1[2];
      #pragma unroll
      for (int ks = 0; ks < 2; ++ks) {
        ka0[ks] = *(const short8*)(Kh + (size_t)(kk + p * 32 + l16) * 64 + ks * 32 + quad * 8);
        ka1[ks] = *(const short8*)(Kh + (size_t)(kk + p * 32 + 16 + l16) * 64 + ks * 32 + quad * 8);
      }
      short8 pt[4];
      #pragma unroll
      for (int qs = 0; qs < 4; ++qs) {
        floatx4 s0 = mfma16(ka0[0], qf[qs][0], fz);
        s0 = mfma16(ka0[1], qf[qs][1], s0);
        floatx4 s1 = mfma16(ka1[0], qf[qs][0], fz);
        s1 = mfma16(ka1[1], qf[qs][1], s1);
        float e0 = __builtin_amdgcn_exp2f(s0[0]);
        float e1 = __builtin_amdgcn_exp2f(s0[1]);
        float e2 = __builtin_amdgcn_exp2f(s0[2]);
        float e3 = __builtin_amdgcn_exp2f(s0[3]);
        float f0 = __builtin_amdgcn_exp2f(s1[0]);
        float f1 = __builtin_amdgcn_exp2f(s1[1]);
        float f2 = __builtin_amdgcn_exp2f(s1[2]);
        float f3 = __builtin_amdgcn_exp2f(s1[3]);
        union { uint4 u; short8 s; } pu;
        pu.u = make_uint4(pk2(e0, e1), pk2(e2, e3), pk2(f0, f1), pk2(f2, f3));
        pt[qs] = pu.s;
      }
      #pragma unroll
      for (int ds = 0; ds < 4; ++ds) {
        short8 va = *(const short8*)(Vh + (size_t)(ds * 16 + l16) * L_ + kk + (p * 4 + quad) * 8);
        #pragma unroll
        for (int qs = 0; qs < 4; ++qs)
          oT[ds][qs] = mfma16(va, pt[qs], oT[ds][qs]);
      }
    }
  }

  // transpose O^T -> O via per-wave private 64x72 LDS region (no cross-wave
  // sharing -> no barrier needed; compiler orders ds_write/ds_read via lgkmcnt)
  u16* ot = smem + w * 4608;   // 64 x 72 u16
  #pragma unroll
  for (int ds = 0; ds < 4; ++ds)
    #pragma unroll
    for (int qs = 0; qs < 4; ++qs)
      #pragma unroll
      for (int r = 0; r < 4; ++r)
        ot[(qs * 16 + l16) * 72 + ds * 16 + quad * 4 + r] = f2bf(oT[ds][qs][r]);
  #pragma unroll
  for (int i = 0; i < 8; ++i) {
    int cc = i * 64 + lane;
    int ql = cc >> 3, d8 = cc & 7;
    short8 v = *(const short8*)(&ot[ql * 72 + d8 * 8]);
    *(short8*)(O + ((size_t)b * L_ + q0 + ql) * D_ + h * HD_ + d8 * 8) = v;
  }
}

extern "C" void kernel_launch(void* const* d_in, const int* in_sizes, int n_in,
                              void* d_out, int out_size, void* d_ws, size_t ws_size,
                              hipStream_t stream) {
  const float* xq = (const float*)d_in[0];
  const float* xk = (const float*)d_in[1];
  const float* xv = (const float*)d_in[2];
  const float* Wq = (const float*)d_in[4];
  const float* bq = (const float*)d_in[5];
  const float* Wk = (const float*)d_in[6];
  const float* bk = (const float*)d_in[7];
  const float* Wv = (const float*)d_in[8];
  const float* bv = (const float*)d_in[9];
  const float* Wo = (const float*)d_in[10];
  const float* bo = (const float*)d_in[11];

  char* ws = (char*)d_ws;
  const size_t MB = 1u << 20;
  dim3 blk(256);
  dim3 gg(64, 8);             // x=mt, y=nt: A-sharers on same XCD

  if (ws_size >= 90 * MB) {
    // fast path (89 MB high-water):
    //  [0,16)   xq_bf  -> Vt (after Q gemm)
    //  [16,32)  xk_bf  -> Ob (after K gemm)
    //  [32,48)  xv_bf
    //  [48,56)  WTq,WTk,WTv,WTo (2MB each)
    //  [56,57)  inv
    //  [57,73)  Q      [73,89) K
    u16* xqb = (u16*)(ws);
    u16* xkb = (u16*)(ws + 16 * MB);
    u16* xvb = (u16*)(ws + 32 * MB);
    u16* WTq = (u16*)(ws + 48 * MB);
    u16* WTk = (u16*)(ws + 50 * MB);
    u16* WTv = (u16*)(ws + 52 * MB);
    u16* WTo = (u16*)(ws + 54 * MB);
    float* invb = (float*)(ws + 56 * MB);
    u16* Qb = (u16*)(ws + 57 * MB);
    u16* Kb = (u16*)(ws + 73 * MB);
    u16* Vtb = (u16*)(ws);
    u16* Ob = (u16*)(ws + 16 * MB);

    cvtx3_k<<<dim3(4096, 3), blk, 0, stream>>>(xq, xk, xv, xqb, xkb, xvb);
    cvtw4_k<<<dim3(16, 16, 4), blk, 0, stream>>>(Wq, Wk, Wv, Wo, WTq, WTk, WTv, WTo);
    gemm2_k<1, 1><<<gg, blk, 0, stream>>>(xqb, WTq, bq, Qb, nullptr, 1.0f);
    gemm2_k<1, 1><<<gg, blk, 0, stream>>>(xkb, WTk, bk, Kb, nullptr, KSCALE);
    colsum2_k<<<dim3(128, 4), blk, 0, stream>>>(Qb, Kb, invb);
    gemm2_k<1, 2><<<gg, blk, 0, stream>>>(xvb, WTv, bv, Vtb, invb, 1.0f);
    attn4_k<<<dim3(128, 4), blk, 0, stream>>>(Qb, Kb, Vtb, Ob);
    gemm2_k<1, 0><<<gg, blk, 0, stream>>>(Ob, WTo, bo, (float*)d_out, nullptr, 1.0f);
  } else {
    // fallback: 64 MB flow (V gemm reads fp32 xv directly)
    const size_t MB16 = 16u << 20;
    u16* Xbf  = (u16*)(ws);
    u16* Vtb  = (u16*)(ws);
    u16* Qb   = (u16*)(ws + MB16);
    u16* WT2  = (u16*)(ws + MB16);
    u16* Kb   = (u16*)(ws + 2 * MB16);
    u16* WT   = (u16*)(ws + 3 * MB16);
    float* invb = (float*)(ws + 3 * MB16 + (2u << 20));
    u16* Ob   = (u16*)(ws + 3 * MB16);

    cvtx3_k<<<dim3(4096, 1), blk, 0, stream>>>(xq, xq, xq, Xbf, Xbf, Xbf);
    cvtw4_k<<<dim3(16, 16, 1), blk, 0, stream>>>(Wq, Wq, Wq, Wq, WT, WT, WT, WT);
    gemm2_k<1, 1><<<gg, blk, 0, stream>>>(Xbf, WT, bq, Qb, nullptr, 1.0f);
    cvtx3_k<<<dim3(4096, 1), blk, 0, stream>>>(xk, xk, xk, Xbf, Xbf, Xbf);
    cvtw4_k<<<dim3(16, 16, 1), blk, 0, stream>>>(Wk, Wk, Wk, Wk, WT, WT, WT, WT);
    gemm2_k<1, 1><<<gg, blk, 0, stream>>>(Xbf, WT, bk, Kb, nullptr, KSCALE);
    colsum2_k<<<dim3(128, 4), blk, 0, stream>>>(Qb, Kb, invb);
    cvtw4_k<<<dim3(16, 16, 1), blk, 0, stream>>>(Wv, Wv, Wv, Wv, WT, WT, WT, WT);
    gemm2_k<0, 2><<<gg, blk, 0, stream>>>(xv, WT, bv, Vtb, invb, 1.0f);
    attn4_k<<<dim3(128, 4), blk, 0, stream>>>(Qb, Kb, Vtb, Ob);
    cvtw4_k<<<dim3(16, 16, 1), blk, 0, stream>>>(Wo, Wo, Wo, Wo, WT2, WT2, WT2, WT2);
    gemm2_k<1, 0><<<gg, blk, 0, stream>>>(Ob, WT2, bo, (float*)d_out, nullptr, 1.0f);
  }
}

// Round 7
// 309.833 us; speedup vs baseline: 1.0906x; 1.0906x over previous
//
#include <hip/hip_runtime.h>
#include <hip/hip_bf16.h>

// B=8, L=1024, D=1024, H=16, HD=64
#define B_ 8
#define L_ 1024
#define D_ 1024
#define H_ 16
#define HD_ 64

typedef short short8 __attribute__((ext_vector_type(8)));
typedef float floatx4 __attribute__((ext_vector_type(4)));
typedef unsigned short u16;

__device__ __forceinline__ u16 f2bf(float f) {          // RNE
  union { float f; unsigned u; } v; v.f = f;
  unsigned r = v.u + 0x7fffu + ((v.u >> 16) & 1u);
  return (u16)(r >> 16);
}
// pack bf16(a) low16, bf16(b) high16
__device__ __forceinline__ unsigned pk2(float a, float b) {
  union { float f; unsigned u; } x, y; x.f = a; y.f = b;
  return __builtin_amdgcn_perm(y.u + 0x8000u, x.u + 0x8000u, 0x07060302u);
}
__device__ __forceinline__ floatx4 mfma16(short8 a, short8 b, floatx4 c) {
  return __builtin_amdgcn_mfma_f32_16x16x32_bf16(a, b, c, 0, 0, 0);
}
__device__ __forceinline__ void gl2lds16(const void* g, void* l) {
  __builtin_amdgcn_global_load_lds(
      (const __attribute__((address_space(1))) void*)g,
      (__attribute__((address_space(3))) void*)l, 16, 0, 0);
}

#define KSCALE 0.04508422f   // log2(e)/32 folded into K projection

// ---- 3x: x fp32 [8M] -> bf16, grid (4096, nsel) ----
__global__ __launch_bounds__(256) void cvtx3_k(const float* __restrict__ x0,
    const float* __restrict__ x1, const float* __restrict__ x2,
    u16* __restrict__ y0, u16* __restrict__ y1, u16* __restrict__ y2) {
  const float* x = blockIdx.y == 0 ? x0 : (blockIdx.y == 1 ? x1 : x2);
  u16* y = blockIdx.y == 0 ? y0 : (blockIdx.y == 1 ? y1 : y2);
  size_t i = ((size_t)blockIdx.x * 256 + threadIdx.x) * 8;
  float4 a = *(const float4*)(x + i);
  float4 b = *(const float4*)(x + i + 4);
  uint4 u = make_uint4(pk2(a.x, a.y), pk2(a.z, a.w), pk2(b.x, b.y), pk2(b.z, b.w));
  *(uint4*)(y + i) = u;
}

// ---- 4x: W [K,N] fp32 -> Wt [N][K] bf16, grid (16,16,4) ----
__global__ __launch_bounds__(256) void cvtw4_k(
    const float* __restrict__ W0, const float* __restrict__ W1,
    const float* __restrict__ W2, const float* __restrict__ W3,
    u16* __restrict__ T0, u16* __restrict__ T1,
    u16* __restrict__ T2, u16* __restrict__ T3) {
  const int z = blockIdx.z;
  const float* W = z == 0 ? W0 : (z == 1 ? W1 : (z == 2 ? W2 : W3));
  u16* Wt = z == 0 ? T0 : (z == 1 ? T1 : (z == 2 ? T2 : T3));
  const int kt = blockIdx.x, nt = blockIdx.y;
  __shared__ __align__(16) u16 t[64 * 72];
  const int tid = threadIdx.x;
  #pragma unroll
  for (int i = 0; i < 4; ++i) {
    int idx = i * 256 + tid;
    int r = idx >> 4, c4 = idx & 15;
    float4 v = *(const float4*)(W + (size_t)(kt * 64 + r) * 1024 + nt * 64 + c4 * 4);
    t[(c4 * 4 + 0) * 72 + r] = f2bf(v.x);
    t[(c4 * 4 + 1) * 72 + r] = f2bf(v.y);
    t[(c4 * 4 + 2) * 72 + r] = f2bf(v.z);
    t[(c4 * 4 + 3) * 72 + r] = f2bf(v.w);
  }
  __syncthreads();
  #pragma unroll
  for (int i = 0; i < 2; ++i) {
    int idx = i * 256 + tid;
    int n = idx >> 3, k8 = idx & 7;
    short8 v = *(const short8*)(&t[n * 72 + k8 * 8]);
    *(short8*)(Wt + (size_t)(nt * 64 + n) * 1024 + kt * 64 + k8 * 8) = v;
  }
}

// ---- GEMM: C[8192,1024] = A @ Wt^T + bias ----  BK=64
// grid (64, 8): x=mt, y=nt -> A-slab sharers land on the same XCD (id%8)
// AMODE: 0 = A fp32, 1 = A bf16
// OUTM : 0 = fp32 [M,N]; 1 = bf16 head [B,H,L,HD], scaled by `scale`;
//        2 = bf16 V^T [B*D][L] scaled by inv[key], keys PERMUTED within
//            32-groups: pos = g*32 + quad*8 + kt*4 + r  <- key g*32+kt*16+quad*4+r
template<int AMODE, int OUTM>
__global__ __launch_bounds__(256, 2) void gemm2_k(const void* __restrict__ Ap,
    const u16* __restrict__ Bt, const float* __restrict__ bias,
    void* __restrict__ Cp, const float* __restrict__ inv, float scale)
{
  const int mt = blockIdx.x, nt = blockIdx.y;
  const int tid = threadIdx.x, lane = tid & 63, w = tid >> 6;
  const int quad = lane >> 4, l16 = lane & 15;
  const int wm = w >> 1, wn = w & 1;
  const int m0 = mt * 128, n0 = nt * 128;

  constexpr int ABYTES = AMODE ? 16384 : 32768;
  constexpr int STG = ABYTES + 16384;
  constexpr int SBYTES = (OUTM == 2 && STG < 34816) ? 34816 : STG;
  __shared__ __align__(16) char smem[SBYTES];
  char* AsB = smem;
  char* BsB = smem + ABYTES;

  const floatx4 fz = {0.f, 0.f, 0.f, 0.f};
  floatx4 acc[4][4];
  #pragma unroll
  for (int i = 0; i < 4; ++i)
    #pragma unroll
    for (int j = 0; j < 4; ++j) acc[i][j] = fz;

  for (int k0 = 0; k0 < 1024; k0 += 64) {
    #pragma unroll
    for (int seg = 0; seg < 4; ++seg) {
      int cI = seg * 256 + w * 64 + lane;
      int r = cI >> 3, sl = cI & 7;
      int kc = sl ^ (r & 7);
      gl2lds16(Bt + (size_t)(n0 + r) * 1024 + k0 + kc * 8, BsB + cI * 16);
    }
    if constexpr (AMODE == 0) {   // A fp32: 128 rows x 256B, 16 slots
      const float* A = (const float*)Ap;
      #pragma unroll
      for (int seg = 0; seg < 8; ++seg) {
        int cI = seg * 256 + w * 64 + lane;
        int r = cI >> 4, sl = cI & 15;
        int kc = sl ^ (r & 15);
        gl2lds16(A + (size_t)(m0 + r) * 1024 + k0 + kc * 4, AsB + cI * 16);
      }
    } else {                      // A bf16: 128 rows x 128B, 8 slots
      const u16* A = (const u16*)Ap;
      #pragma unroll
      for (int seg = 0; seg < 4; ++seg) {
        int cI = seg * 256 + w * 64 + lane;
        int r = cI >> 3, sl = cI & 7;
        int kc = sl ^ (r & 7);
        gl2lds16(A + (size_t)(m0 + r) * 1024 + k0 + kc * 8, AsB + cI * 16);
      }
    }
    __syncthreads();

    #pragma unroll
    for (int ks = 0; ks < 2; ++ks) {
      short8 af[4], bfv[4];
      #pragma unroll
      for (int mf = 0; mf < 4; ++mf) {
        int row = wm * 64 + mf * 16 + l16;
        if constexpr (AMODE == 0) {
          int L0 = ks * 8 + quad * 2;
          float4 x0 = *(const float4*)(AsB + row * 256 + ((L0) ^ l16) * 16);
          float4 x1 = *(const float4*)(AsB + row * 256 + ((L0 + 1) ^ l16) * 16);
          union { uint4 u; short8 s; } uu;
          uu.u = make_uint4(pk2(x0.x, x0.y), pk2(x0.z, x0.w),
                            pk2(x1.x, x1.y), pk2(x1.z, x1.w));
          af[mf] = uu.s;
        } else {
          af[mf] = *(const short8*)(AsB + row * 128 + (((ks * 4 + quad) ^ (l16 & 7)) * 16));
        }
      }
      #pragma unroll
      for (int nf = 0; nf < 4; ++nf) {
        int row = wn * 64 + nf * 16 + l16;
        bfv[nf] = *(const short8*)(BsB + row * 128 + (((ks * 4 + quad) ^ (l16 & 7)) * 16));
      }
      #pragma unroll
      for (int mf = 0; mf < 4; ++mf)
        #pragma unroll
        for (int nf = 0; nf < 4; ++nf)
          acc[mf][nf] = mfma16(af[mf], bfv[nf], acc[mf][nf]);
    }
    __syncthreads();
  }

  float bv[4];
  #pragma unroll
  for (int nf = 0; nf < 4; ++nf) bv[nf] = bias[n0 + wn * 64 + nf * 16 + l16];

  if constexpr (OUTM == 0) {
    float* C = (float*)Cp;
    #pragma unroll
    for (int mf = 0; mf < 4; ++mf)
      #pragma unroll
      for (int nf = 0; nf < 4; ++nf) {
        int n = n0 + wn * 64 + nf * 16 + l16;
        #pragma unroll
        for (int r = 0; r < 4; ++r) {
          int m = m0 + wm * 64 + mf * 16 + quad * 4 + r;
          C[(size_t)m * 1024 + n] = acc[mf][nf][r] + bv[nf];
        }
      }
  } else if constexpr (OUTM == 1) {
    u16* C = (u16*)Cp;
    #pragma unroll
    for (int mf = 0; mf < 4; ++mf)
      #pragma unroll
      for (int nf = 0; nf < 4; ++nf) {
        int n = n0 + wn * 64 + nf * 16 + l16;
        #pragma unroll
        for (int r = 0; r < 4; ++r) {
          int m = m0 + wm * 64 + mf * 16 + quad * 4 + r;
          int bb = m >> 10, l = m & 1023, hh = n >> 6, hd = n & 63;
          C[((size_t)((bb * H_ + hh) * L_) + l) * HD_ + hd] =
              f2bf((acc[mf][nf][r] + bv[nf]) * scale);
        }
      }
  } else {  // OUTM == 2: scaled V^T, permuted key order
    u16* ct = (u16*)smem;            // 128 x 136 u16
    const int bb = m0 >> 10;
    const int hrow = bb * 16 + (n0 >> 6) + wn;
    float ivv[4][4];
    #pragma unroll
    for (int mf = 0; mf < 4; ++mf)
      #pragma unroll
      for (int r = 0; r < 4; ++r)
        ivv[mf][r] = inv[(size_t)hrow * 1024 + (m0 & 1023) + wm * 64 + mf * 16 + quad * 4 + r];
    __syncthreads();
    #pragma unroll
    for (int mf = 0; mf < 4; ++mf)
      #pragma unroll
      for (int nf = 0; nf < 4; ++nf)
        #pragma unroll
        for (int r = 0; r < 4; ++r) {
          float val = (acc[mf][nf][r] + bv[nf]) * ivv[mf][r];
          ct[(wn * 64 + nf * 16 + l16) * 136 + wm * 64 + mf * 16 + quad * 4 + r] = f2bf(val);
        }
    __syncthreads();
    u16* Vt = (u16*)Cp;
    #pragma unroll
    for (int i = 0; i < 8; ++i) {
      int cc = i * 256 + tid;
      int n = cc >> 4, l8 = cc & 15;
      int g = l8 >> 2, q2 = l8 & 3;
      int mloc = g * 32 + q2 * 4;
      uint2 lo = *(const uint2*)(&ct[n * 136 + mloc]);
      uint2 hi = *(const uint2*)(&ct[n * 136 + mloc + 16]);
      uint4 uv = make_uint4(lo.x, lo.y, hi.x, hi.y);
      *(uint4*)(Vt + ((size_t)bb * 1024 + n0 + n) * 1024 + (m0 & 1023) + l8 * 8) = uv;
    }
  }
}

// ---- colsum: inv[b,h,k] = 1/sum_q exp2(S'[q,k]); K pre-scaled by log2e/32 ----
// grid (128, 4): x = head (same-head blocks share an XCD), y = ktb
__global__ __launch_bounds__(256, 2) void colsum2_k(const u16* __restrict__ Q,
    const u16* __restrict__ K, float* __restrict__ inv)
{
  const int hh = blockIdx.x, ktb = blockIdx.y;
  const int tid = threadIdx.x, lane = tid & 63, w = tid >> 6;
  const int quad = lane >> 4, l16 = lane & 15;
  const size_t hb = (size_t)hh * L_ * HD_;
  const u16* Qh = Q + hb;
  const u16* Kh = K + hb;
  const int kbase = ktb * 256 + w * 64;
  const floatx4 fz = {0.f, 0.f, 0.f, 0.f};

  __shared__ __align__(16) u16 qsm[16384];   // 256 q-rows x 64 bf16, swizzled

  short8 kf[4][2];
  #pragma unroll
  for (int nf = 0; nf < 4; ++nf)
    #pragma unroll
    for (int ks = 0; ks < 2; ++ks)
      kf[nf][ks] = *(const short8*)(Kh + (size_t)(kbase + nf * 16 + l16) * 64 + ks * 32 + quad * 8);

  float cs[4] = {0.f, 0.f, 0.f, 0.f};
  for (int qc = 0; qc < 4; ++qc) {
    #pragma unroll
    for (int seg = 0; seg < 8; ++seg) {
      int cI = seg * 256 + w * 64 + lane;
      int row = cI >> 3, sl = cI & 7;
      gl2lds16(Qh + (size_t)(qc * 256 + row) * 64 + ((sl ^ (row & 7)) * 8), (char*)qsm + cI * 16);
    }
    __syncthreads();
    #pragma unroll
    for (int mf = 0; mf < 16; ++mf) {
      short8 qf0 = *(const short8*)(&qsm[(mf * 16 + l16) * 64 + ((quad ^ (l16 & 7)) * 8)]);
      short8 qf1 = *(const short8*)(&qsm[(mf * 16 + l16) * 64 + (((4 + quad) ^ (l16 & 7)) * 8)]);
      floatx4 sacc[4];
      #pragma unroll
      for (int nf = 0; nf < 4; ++nf) {
        floatx4 s = mfma16(qf0, kf[nf][0], fz);
        sacc[nf] = mfma16(qf1, kf[nf][1], s);
      }
      #pragma unroll
      for (int nf = 0; nf < 4; ++nf)
        #pragma unroll
        for (int r = 0; r < 4; ++r)
          cs[nf] += __builtin_amdgcn_exp2f(sacc[nf][r]);
    }
    __syncthreads();
  }
  #pragma unroll
  for (int nf = 0; nf < 4; ++nf) {
    cs[nf] += __shfl_xor(cs[nf], 16);
    cs[nf] += __shfl_xor(cs[nf], 32);
  }
  if (quad == 0) {
    #pragma unroll
    for (int nf = 0; nf < 4; ++nf)
      inv[(size_t)hh * L_ + kbase + nf * 16 + l16] = 1.0f / cs[nf];
  }
}

// ---- attention: counted-vmcnt TRIPLE-buffered K/V staging, 64-key chunks ----
// grid (128, 4): x = head, y = qb (256 q-rows/block, 64/wave).
// Per stage each thread issues exactly 4 global_load_lds (2 K + 2 V).
// Pipeline: prefetch distance 2; per iter: wait vmcnt(4) [chunk kc's loads
// retired, chunk kc+1's still in flight], raw s_barrier, stage kc+2 into the
// buffer freed by compute(kc-1), compute kc. Only iter 15 drains to 0.
__global__ __launch_bounds__(256, 2) void attn5_k(const u16* __restrict__ Q,
    const u16* __restrict__ K, const u16* __restrict__ Vt, u16* __restrict__ O)
{
  const int hh = blockIdx.x, qb = blockIdx.y;
  const int b = hh >> 4, h = hh & 15;
  const int tid = threadIdx.x, lane = tid & 63, w = tid >> 6;
  const int quad = lane >> 4, l16 = lane & 15;
  const size_t hb = (size_t)hh * L_ * HD_;
  const u16* Qh = Q + hb;
  const u16* Kh = K + hb;
  const u16* Vh = Vt + ((size_t)b * D_ + h * HD_) * L_;   // [d][pos], stride L
  const int q0 = qb * 256 + w * 64;
  const floatx4 fz = {0.f, 0.f, 0.f, 0.f};

  // 3 buffers x 16KB (K 8KB + V 8KB); epilogue (36864B) reuses the region.
  __shared__ __align__(16) u16 smem[24576];

  short8 qf[4][2];            // B-operand frags of Q
  #pragma unroll
  for (int qs = 0; qs < 4; ++qs)
    #pragma unroll
    for (int ks = 0; ks < 2; ++ks)
      qf[qs][ks] = *(const short8*)(Qh + (size_t)(q0 + qs * 16 + l16) * 64 + ks * 32 + quad * 8);

  floatx4 oT[4][4];           // O^T: row d=ds*16+quad*4+r, col q=qs*16+l16
  #pragma unroll
  for (int i = 0; i < 4; ++i)
    #pragma unroll
    for (int j = 0; j < 4; ++j) oT[i][j] = fz;

  // stage 64-key chunk kc into buffer buf (4 gl2lds per thread)
  auto stage = [&](int kc, int buf) {
    const int kk = kc * 64;
    char* kdst = (char*)smem + buf * 16384;
    char* vdst = kdst + 8192;
    #pragma unroll
    for (int seg = 0; seg < 2; ++seg) {       // K: 64 rows x 128B, 8 slots
      int cI = seg * 256 + w * 64 + lane;
      int row = cI >> 3, sl = cI & 7;
      gl2lds16(Kh + (size_t)(kk + row) * 64 + ((sl ^ (row & 7)) * 8), kdst + cI * 16);
    }
    #pragma unroll
    for (int seg = 0; seg < 2; ++seg) {       // V: 64 d-rows x 128B, 8 slots
      int cI = seg * 256 + w * 64 + lane;
      int row = cI >> 3, sl = cI & 7;
      gl2lds16(Vh + (size_t)row * L_ + kk + ((sl ^ (row & 7)) * 8), vdst + cI * 16);
    }
  };

  stage(0, 0);
  stage(1, 1);
  for (int kc = 0; kc < 16; ++kc) {
    if (kc < 15) asm volatile("s_waitcnt vmcnt(4)" ::: "memory");
    else         asm volatile("s_waitcnt vmcnt(0)" ::: "memory");
    __builtin_amdgcn_s_barrier();
    asm volatile("" ::: "memory");            // no ds_read hoists above barrier
    if (kc < 14) stage(kc + 2, (kc + 2) % 3);
    char* ksb = (char*)smem + (kc % 3) * 16384;
    char* vsb = ksb + 8192;

    #pragma unroll
    for (int p = 0; p < 2; ++p) {             // 2 groups of 32 keys
      short8 ka0[2], ka1[2];
      #pragma unroll
      for (int ks = 0; ks < 2; ++ks) {
        ka0[ks] = *(const short8*)(ksb + (p * 32 + l16) * 128 + (((ks * 4 + quad) ^ (l16 & 7)) * 16));
        ka1[ks] = *(const short8*)(ksb + (p * 32 + 16 + l16) * 128 + (((ks * 4 + quad) ^ (l16 & 7)) * 16));
      }
      short8 pt[4];
      #pragma unroll
      for (int qs = 0; qs < 4; ++qs) {
        floatx4 s0 = mfma16(ka0[0], qf[qs][0], fz);
        s0 = mfma16(ka0[1], qf[qs][1], s0);
        floatx4 s1 = mfma16(ka1[0], qf[qs][0], fz);
        s1 = mfma16(ka1[1], qf[qs][1], s1);
        float e0 = __builtin_amdgcn_exp2f(s0[0]);
        float e1 = __builtin_amdgcn_exp2f(s0[1]);
        float e2 = __builtin_amdgcn_exp2f(s0[2]);
        float e3 = __builtin_amdgcn_exp2f(s0[3]);
        float f0 = __builtin_amdgcn_exp2f(s1[0]);
        float f1 = __builtin_amdgcn_exp2f(s1[1]);
        float f2 = __builtin_amdgcn_exp2f(s1[2]);
        float f3 = __builtin_amdgcn_exp2f(s1[3]);
        union { uint4 u; short8 s; } pu;
        pu.u = make_uint4(pk2(e0, e1), pk2(e2, e3), pk2(f0, f1), pk2(f2, f3));
        pt[qs] = pu.s;
      }
      #pragma unroll
      for (int ds = 0; ds < 4; ++ds) {
        short8 va = *(const short8*)(vsb + (ds * 16 + l16) * 128 + (((p * 4 + quad) ^ (l16 & 7)) * 16));
        #pragma unroll
        for (int qs = 0; qs < 4; ++qs)
          oT[ds][qs] = mfma16(va, pt[qs], oT[ds][qs]);
      }
    }
  }
  __syncthreads();   // epilogue aliases the staging buffers

  // transpose O^T -> O via per-wave LDS region (r0-verbatim epilogue)
  u16* ot = smem + w * 4608;   // 64 x 72 u16
  #pragma unroll
  for (int ds = 0; ds < 4; ++ds)
    #pragma unroll
    for (int qs = 0; qs < 4; ++qs)
      #pragma unroll
      for (int r = 0; r < 4; ++r)
        ot[(qs * 16 + l16) * 72 + ds * 16 + quad * 4 + r] = f2bf(oT[ds][qs][r]);
  __syncthreads();
  #pragma unroll
  for (int i = 0; i < 8; ++i) {
    int cc = i * 64 + lane;
    int ql = cc >> 3, d8 = cc & 7;
    short8 v = *(const short8*)(&ot[ql * 72 + d8 * 8]);
    *(short8*)(O + ((size_t)b * L_ + q0 + ql) * D_ + h * HD_ + d8 * 8) = v;
  }
}

extern "C" void kernel_launch(void* const* d_in, const int* in_sizes, int n_in,
                              void* d_out, int out_size, void* d_ws, size_t ws_size,
                              hipStream_t stream) {
  const float* xq = (const float*)d_in[0];
  const float* xk = (const float*)d_in[1];
  const float* xv = (const float*)d_in[2];
  const float* Wq = (const float*)d_in[4];
  const float* bq = (const float*)d_in[5];
  const float* Wk = (const float*)d_in[6];
  const float* bk = (const float*)d_in[7];
  const float* Wv = (const float*)d_in[8];
  const float* bv = (const float*)d_in[9];
  const float* Wo = (const float*)d_in[10];
  const float* bo = (const float*)d_in[11];

  char* ws = (char*)d_ws;
  const size_t MB = 1u << 20;
  dim3 blk(256);
  dim3 gg(64, 8);             // x=mt, y=nt: A-sharers on same XCD

  if (ws_size >= 90 * MB) {
    // fast path (89 MB high-water):
    //  [0,16)   xq_bf  -> Vt (after Q gemm)
    //  [16,32)  xk_bf  -> Ob (after K gemm)
    //  [32,48)  xv_bf
    //  [48,56)  WTq,WTk,WTv,WTo (2MB each)
    //  [56,57)  inv
    //  [57,73)  Q      [73,89) K
    u16* xqb = (u16*)(ws);
    u16* xkb = (u16*)(ws + 16 * MB);
    u16* xvb = (u16*)(ws + 32 * MB);
    u16* WTq = (u16*)(ws + 48 * MB);
    u16* WTk = (u16*)(ws + 50 * MB);
    u16* WTv = (u16*)(ws + 52 * MB);
    u16* WTo = (u16*)(ws + 54 * MB);
    float* invb = (float*)(ws + 56 * MB);
    u16* Qb = (u16*)(ws + 57 * MB);
    u16* Kb = (u16*)(ws + 73 * MB);
    u16* Vtb = (u16*)(ws);
    u16* Ob = (u16*)(ws + 16 * MB);

    cvtx3_k<<<dim3(4096, 3), blk, 0, stream>>>(xq, xk, xv, xqb, xkb, xvb);
    cvtw4_k<<<dim3(16, 16, 4), blk, 0, stream>>>(Wq, Wk, Wv, Wo, WTq, WTk, WTv, WTo);
    gemm2_k<1, 1><<<gg, blk, 0, stream>>>(xqb, WTq, bq, Qb, nullptr, 1.0f);
    gemm2_k<1, 1><<<gg, blk, 0, stream>>>(xkb, WTk, bk, Kb, nullptr, KSCALE);
    colsum2_k<<<dim3(128, 4), blk, 0, stream>>>(Qb, Kb, invb);
    gemm2_k<1, 2><<<gg, blk, 0, stream>>>(xvb, WTv, bv, Vtb, invb, 1.0f);
    attn5_k<<<dim3(128, 4), blk, 0, stream>>>(Qb, Kb, Vtb, Ob);
    gemm2_k<1, 0><<<gg, blk, 0, stream>>>(Ob, WTo, bo, (float*)d_out, nullptr, 1.0f);
  } else {
    // fallback: 64 MB flow (V gemm reads fp32 xv directly)
    const size_t MB16 = 16u << 20;
    u16* Xbf  = (u16*)(ws);
    u16* Vtb  = (u16*)(ws);
    u16* Qb   = (u16*)(ws + MB16);
    u16* WT2  = (u16*)(ws + MB16);
    u16* Kb   = (u16*)(ws + 2 * MB16);
    u16* WT   = (u16*)(ws + 3 * MB16);
    float* invb = (float*)(ws + 3 * MB16 + (2u << 20));
    u16* Ob   = (u16*)(ws + 3 * MB16);

    cvtx3_k<<<dim3(4096, 1), blk, 0, stream>>>(xq, xq, xq, Xbf, Xbf, Xbf);
    cvtw4_k<<<dim3(16, 16, 1), blk, 0, stream>>>(Wq, Wq, Wq, Wq, WT, WT, WT, WT);
    gemm2_k<1, 1><<<gg, blk, 0, stream>>>(Xbf, WT, bq, Qb, nullptr, 1.0f);
    cvtx3_k<<<dim3(4096, 1), blk, 0, stream>>>(xk, xk, xk, Xbf, Xbf, Xbf);
    cvtw4_k<<<dim3(16, 16, 1), blk, 0, stream>>>(Wk, Wk, Wk, Wk, WT, WT, WT, WT);
    gemm2_k<1, 1><<<gg, blk, 0, stream>>>(Xbf, WT, bk, Kb, nullptr, KSCALE);
    colsum2_k<<<dim3(128, 4), blk, 0, stream>>>(Qb, Kb, invb);
    cvtw4_k<<<dim3(16, 16, 1), blk, 0, stream>>>(Wv, Wv, Wv, Wv, WT, WT, WT, WT);
    gemm2_k<0, 2><<<gg, blk, 0, stream>>>(xv, WT, bv, Vtb, invb, 1.0f);
    attn5_k<<<dim3(128, 4), blk, 0, stream>>>(Qb, Kb, Vtb, Ob);
    cvtw4_k<<<dim3(16, 16, 1), blk, 0, stream>>>(Wo, Wo, Wo, Wo, WT2, WT2, WT2, WT2);
    gemm2_k<1, 0><<<gg, blk, 0, stream>>>(Ob, WT2, bo, (float*)d_out, nullptr, 1.0f);
  }
}